// Round 1
// baseline (568.463 us; speedup 1.0000x reference)
//
#include <hip/hip_runtime.h>

// Problem constants (from reference): S=64 grid, B=8 batch.
#define SGRID 64
#define SS 4096        // S*S
#define BATCH 8

// One thread per (b, pixel). Each thread:
//  - reads gt_flow (2), vis_mask (1)
//  - computes 4 corner indices + bilinear weights + last-writer-wins keep mask
//  - gathers 4 corr values from corr_m[b, pix, idx_i]
//  - for c in 0..2 gathers ref_v[b,c,idx_i], forms the two <=4-term dot products
//  - writes out[0][b][c][pix] and out[1][b][c][pix]
__global__ __launch_bounds__(256)
void smpl_loss_kernel(const float* __restrict__ corr_m,
                      const float* __restrict__ gt_flow,
                      const float* __restrict__ vis_mask,
                      const float* __restrict__ scale_ref,
                      float* __restrict__ out) {
    int t = blockIdx.x * blockDim.x + threadIdx.x;
    if (t >= BATCH * SS) return;
    int b   = t >> 12;      // t / 4096
    int pix = t & 4095;     // t % 4096

    // gt_flow layout [B,2,64,64] -> [B,2,4096]
    float g0 = gt_flow[(size_t)b * 2 * SS + pix];        // x-flow
    float g1 = gt_flow[(size_t)b * 2 * SS + SS + pix];   // y-flow
    float gx = (g0 + 1.0f) * (float)(SGRID - 1) * 0.5f;
    float gy = (g1 + 1.0f) * (float)(SGRID - 1) * 0.5f;
    float fx = floorf(gx);
    float fy = floorf(gy);

    // corners: x (row) from fy+ox, y (col) from fx+oy; offsets (ox,oy) = (0,0),(0,1),(1,0),(1,1)
    float x0 = fminf(fmaxf(fy,       0.0f), (float)(SGRID - 1));
    float x1 = fminf(fmaxf(fy + 1.f, 0.0f), (float)(SGRID - 1));
    float y0 = fminf(fmaxf(fx,       0.0f), (float)(SGRID - 1));
    float y1 = fminf(fmaxf(fx + 1.f, 0.0f), (float)(SGRID - 1));

    int idx[4];
    idx[0] = (int)(x0 * (float)SGRID + y0);
    idx[1] = (int)(x0 * (float)SGRID + y1);
    idx[2] = (int)(x1 * (float)SGRID + y0);
    idx[3] = (int)(x1 * (float)SGRID + y1);

    float w[4];
    w[0] = (fy + 1.0f - gy) * (fx + 1.0f - gx);
    w[1] = (fy + 1.0f - gy) * (gx - fx);
    w[2] = (gy - fy) * (fx + 1.0f - gx);
    w[3] = (gy - fy) * (gx - fx);

    // sequential scatter-with-set semantics: last corner writing a channel wins
    bool keep[4];
    keep[3] = true;
    keep[2] = (idx[2] != idx[3]);
    keep[1] = (idx[1] != idx[2]) && (idx[1] != idx[3]);
    keep[0] = (idx[0] != idx[1]) && (idx[0] != idx[2]) && (idx[0] != idx[3]);

    // corr_view[b, m, i, j] = corr_m[b, i*64+j, m]  -> gather along last dim of row (b,pix)
    const float* corr_row = corr_m + (size_t)b * SS * SS + (size_t)pix * SS;
    float cv[4];
#pragma unroll
    for (int i = 0; i < 4; ++i) cv[i] = corr_row[idx[i]];

    float vis = vis_mask[(size_t)b * SS + pix];

    const float* ref_b = scale_ref + (size_t)b * 3 * SS;
#pragma unroll
    for (int c = 0; c < 3; ++c) {
        const float* refc = ref_b + (size_t)c * SS;
        float s_gts = 0.0f;  // warp_smpl accumulator
        float s_cyc = 0.0f;  // warp_corr accumulator
#pragma unroll
        for (int i = 0; i < 4; ++i) {
            if (keep[i]) {
                float r = refc[idx[i]];
                s_gts += w[i]  * r;
                s_cyc += cv[i] * r;
            }
        }
        // out shape [2, B, 3, 64, 64], flat
        out[((size_t)(0 * BATCH + b) * 3 + c) * SS + pix] = s_gts * vis;
        out[((size_t)(1 * BATCH + b) * 3 + c) * SS + pix] = s_cyc * vis;
    }
}

extern "C" void kernel_launch(void* const* d_in, const int* in_sizes, int n_in,
                              void* d_out, int out_size, void* d_ws, size_t ws_size,
                              hipStream_t stream) {
    const float* corr_m    = (const float*)d_in[0];
    const float* gt_flow   = (const float*)d_in[1];
    const float* vis_mask  = (const float*)d_in[2];
    const float* scale_ref = (const float*)d_in[3];
    float* out = (float*)d_out;

    const int total = BATCH * SS;           // 32768 threads
    const int block = 256;
    const int grid  = (total + block - 1) / block;  // 128 blocks
    smpl_loss_kernel<<<grid, block, 0, stream>>>(corr_m, gt_flow, vis_mask, scale_ref, out);
}